// Round 3
// baseline (390.158 us; speedup 1.0000x reference)
//
#include <hip/hip_runtime.h>

typedef float f32x4 __attribute__((ext_vector_type(4)));

#define M_ROWS 131072
#define N_COLS 512
#define K_DIM  64
#define MCHUNK 128   // m rows per block
#define TM     8     // m rows per inner iteration

// 0.5*tanh(p) = 0.5 - 1/(exp2(p*2*log2 e)+1); exact at 0 and saturates correctly.
__device__ __forceinline__ float half_tanh(float p) {
  float t = __builtin_amdgcn_exp2f(p * 2.8853900817779268f);
  return 0.5f - __builtin_amdgcn_rcpf(t + 1.0f);
}

__global__ __launch_bounds__(512) void esn_valu(const float* __restrict__ x,
                                                const float* __restrict__ w,
                                                float* __restrict__ out) {
  const int tid  = threadIdx.x;
  const int wv   = tid >> 6;          // 8 waves
  const int lane = tid & 63;
  const int r    = (wv << 6) + lane;  // this lane's output column, 0..511

  // ---- w row held in VGPRs for the whole block (16 x dwordx4) ----
  f32x4 wr[16];
  const f32x4* wp = (const f32x4*)(w + (size_t)r * K_DIM);
#pragma unroll
  for (int i = 0; i < 16; ++i) wr[i] = wp[i];

  const int m0 = blockIdx.x * MCHUNK;
#pragma unroll 1
  for (int mi = 0; mi < MCHUNK; mi += TM) {
    const int m = m0 + mi;
    // x rows m..m+TM-1 are contiguous; addresses are wave-uniform -> s_load.
    const f32x4* xp = (const f32x4*)(x + (size_t)m * K_DIM);

    float acc[TM];
#pragma unroll
    for (int t = 0; t < TM; ++t) acc[t] = 0.f;

#pragma unroll
    for (int kc = 0; kc < 16; ++kc) {
      const f32x4 wv4 = wr[kc];
#pragma unroll
      for (int t = 0; t < TM; ++t) {
        const f32x4 xv = xp[t * 16 + kc];   // x[m+t][4*kc .. 4*kc+3], uniform
#pragma unroll
        for (int j = 0; j < 4; ++j) acc[t] = fmaf(xv[j], wv4[j], acc[t]);
      }
    }

    float* op = out + (size_t)m * N_COLS + r;
#pragma unroll
    for (int t = 0; t < TM; ++t) op[(size_t)t * N_COLS] = half_tanh(acc[t]);
  }
}

extern "C" void kernel_launch(void* const* d_in, const int* in_sizes, int n_in,
                              void* d_out, int out_size, void* d_ws, size_t ws_size,
                              hipStream_t stream) {
  const float* x = (const float*)d_in[0];   // [131072, 64]
  const float* w = (const float*)d_in[1];   // [512, 64]
  // d_in[2] (d) is dead: reference state is identically zero.
  float* out = (float*)d_out;               // [131072, 512]

  dim3 grid(M_ROWS / MCHUNK);   // 1024 blocks
  dim3 block(512);              // 8 waves: wave w covers r in [64w, 64w+64)
  hipLaunchKernelGGL(esn_valu, grid, block, 0, stream, x, w, out);
}

// Round 4
// 180.811 us; speedup vs baseline: 2.1578x; 2.1578x over previous
//
#include <hip/hip_runtime.h>

typedef float f32x4 __attribute__((ext_vector_type(4)));

#define M_ROWS 131072
#define N_COLS 512
#define K_DIM  64
#define MCHUNK 128             // m rows per block
#define TM     8               // m rows per inner chunk
#define NCHUNK (MCHUNK / TM)   // 16

// 0.5*tanh(p) = 0.5 - 1/(exp2(p*2*log2 e)+1); exact at 0, saturates correctly.
__device__ __forceinline__ float half_tanh(float p) {
  float t = __builtin_amdgcn_exp2f(p * 2.8853900817779268f);
  return 0.5f - __builtin_amdgcn_rcpf(t + 1.0f);
}

__global__ __launch_bounds__(256, 3) void esn_valu(const float* __restrict__ x,
                                                   const float* __restrict__ w,
                                                   float* __restrict__ out) {
  const int tid = threadIdx.x;
  // 4 waves cover 256 consecutive r; blockIdx.y picks which half of N.
  const int r = blockIdx.y * 256 + tid;

  // ---- w row: 64 floats in VGPRs, pinned so the compiler cannot re-sink ----
  f32x4 wr[16];
  const f32x4* wp = (const f32x4*)(w + (size_t)r * K_DIM);
#pragma unroll
  for (int i = 0; i < 16; ++i) wr[i] = wp[i];
#pragma unroll
  for (int i = 0; i < 16; ++i) asm volatile("" : "+v"(wr[i]));

  const int m0 = blockIdx.x * MCHUNK;
  const f32x4* xb = (const f32x4*)(x + (size_t)m0 * K_DIM);  // 16 f32x4 per row

  // Double-buffered x groups: group(kc) = { x[m+t][4kc..4kc+3] : t=0..TM-1 }
  f32x4 xA[TM], xB[TM];
#pragma unroll
  for (int t = 0; t < TM; ++t) xA[t] = xb[t * 16];   // chunk 0, kc 0

#pragma unroll 1
  for (int c = 0; c < NCHUNK; ++c) {
    const f32x4* xc = xb + (size_t)c * TM * 16;
    float acc[TM];
#pragma unroll
    for (int t = 0; t < TM; ++t) acc[t] = 0.f;

#pragma unroll
    for (int kc = 0; kc < 16; kc += 2) {
      // even step: prefetch group(kc+1) into xB, compute group(kc) from xA
#pragma unroll
      for (int t = 0; t < TM; ++t) xB[t] = xc[t * 16 + kc + 1];
#pragma unroll
      for (int t = 0; t < TM; ++t) {
        const f32x4 xv = xA[t], wv = wr[kc];
#pragma unroll
        for (int j = 0; j < 4; ++j) acc[t] = fmaf(xv[j], wv[j], acc[t]);
      }
      // odd step: prefetch group(kc+2) (or next chunk's kc=0) into xA,
      //           compute group(kc+1) from xB
      const f32x4* nxt = (kc == 14)
                             ? (xc + ((c == NCHUNK - 1) ? 0 : TM * 16))
                             : (xc + kc + 2);
#pragma unroll
      for (int t = 0; t < TM; ++t) xA[t] = nxt[t * 16];
#pragma unroll
      for (int t = 0; t < TM; ++t) {
        const f32x4 xv = xB[t], wv = wr[kc + 1];
#pragma unroll
        for (int j = 0; j < 4; ++j) acc[t] = fmaf(xv[j], wv[j], acc[t]);
      }
    }

    float* op = out + (size_t)(m0 + c * TM) * N_COLS + r;
#pragma unroll
    for (int t = 0; t < TM; ++t) op[(size_t)t * N_COLS] = half_tanh(acc[t]);
  }
}

extern "C" void kernel_launch(void* const* d_in, const int* in_sizes, int n_in,
                              void* d_out, int out_size, void* d_ws, size_t ws_size,
                              hipStream_t stream) {
  const float* x = (const float*)d_in[0];   // [131072, 64]
  const float* w = (const float*)d_in[1];   // [512, 64]
  // d_in[2] (d) is dead: reference state is identically zero.
  float* out = (float*)d_out;               // [131072, 512]

  dim3 grid(M_ROWS / MCHUNK, 2);   // (1024, 2)
  dim3 block(256);                 // 4 waves; wave w covers r 64w..64w+63 within half
  hipLaunchKernelGGL(esn_valu, grid, block, 0, stream, x, w, out);
}